// Round 6
// baseline (602.478 us; speedup 1.0000x reference)
//
#include <hip/hip_runtime.h>

// Round 6: first execution (r5) failed with absmax err 8.5625 ~= max|ref| => likely
// the silent workspace guard (needed 369MB) returned without launching anything.
// Changes: (1) plain bf16 GEMM (tolerance is bf16-scale: 0.17), (2) chunked act
// buffer with ws tiers 185/118/84/67 MB, (3) same verified router/topk/LN graph.
// Attention branch in the reference is dead code (second scatter overwrites first).

typedef unsigned short U16;
typedef __attribute__((ext_vector_type(8))) short short8;   // 8 bf16 in 4 VGPRs
typedef __attribute__((ext_vector_type(4))) float f32x4;

// ---------- helpers ----------
__device__ __forceinline__ U16 bf_hi(float f) {           // fp32 -> bf16 RNE
  unsigned u = __float_as_uint(f);
  unsigned r = u + 0x7FFFu + ((u >> 16) & 1u);
  return (U16)(r >> 16);
}

__device__ __forceinline__ float gelu_f(float x) {
  float z = 0.7978845608028654f * (x + 0.044715f * x * x * x);
  float az = fabsf(z);
  float e = __expf(2.0f * az);          // e==inf safe: 2/(inf+1)=0 -> tanh=+-1
  float t = 1.0f - 2.0f / (e + 1.0f);
  t = (z < 0.0f) ? -t : t;
  return 0.5f * x * (1.0f + t);
}

__device__ __forceinline__ void gl_lds16(const void* g, void* l) {
  __builtin_amdgcn_global_load_lds((const __attribute__((address_space(1))) void*)g,
                                   (__attribute__((address_space(3))) void*)l, 16, 0, 0);
}

// block = 256 (4 waves). Returns total sum to ALL threads. sbuf: >=4 floats.
__device__ __forceinline__ float block_sum(float v, float* sbuf, int tid) {
  #pragma unroll
  for (int o = 32; o > 0; o >>= 1) v += __shfl_down(v, o, 64);
  if ((tid & 63) == 0) sbuf[tid >> 6] = v;
  __syncthreads();
  v = sbuf[0] + sbuf[1] + sbuf[2] + sbuf[3];
  __syncthreads();
  return v;
}

// ---------- 1. router scores ----------
__global__ __launch_bounds__(256) void router_kernel(const float* __restrict__ x,
    const float* __restrict__ rw, const float* __restrict__ rb, float* __restrict__ rs) {
  int w = threadIdx.x >> 6, l = threadIdx.x & 63;
  int t = blockIdx.x * 4 + w;                   // 16384 tokens, 4/block
  const float4* xr  = (const float4*)(x + (size_t)t * 1024);
  const float4* rw4 = (const float4*)rw;
  float s = 0.f;
  #pragma unroll
  for (int i = 0; i < 4; i++) {
    float4 a = xr[l + i * 64], b = rw4[l + i * 64];
    s += a.x * b.x + a.y * b.y + a.z * b.z + a.w * b.w;
  }
  #pragma unroll
  for (int o = 32; o > 0; o >>= 1) s += __shfl_down(s, o, 64);
  if (l == 0) rs[t] = s + rb[0];
}

// ---------- 2. per-batch top-512 -> flags (lax.top_k tie semantics) ----------
__global__ __launch_bounds__(1024) void topk_kernel(const float* __restrict__ rscore,
                                                    int* __restrict__ flags) {
  __shared__ float s[2048];
  __shared__ int sFG, sFE;
  int b = blockIdx.x, tid = threadIdx.x;
  const float* rs = rscore + b * 2048;
  s[tid] = rs[tid];
  s[tid + 1024] = rs[tid + 1024];
  if (tid == 0) { sFG = 2048; sFE = 2048; }
  __syncthreads();
  for (int k = 2; k <= 2048; k <<= 1) {         // bitonic ascending
    for (int j = k >> 1; j > 0; j >>= 1) {
      #pragma unroll
      for (int h = 0; h < 2; h++) {
        int i = tid + h * 1024;
        int p = i ^ j;
        if (p > i) {
          float a = s[i], c = s[p];
          bool up = ((i & k) == 0);
          if ((a > c) == up) { s[i] = c; s[p] = a; }
        }
      }
      __syncthreads();
    }
  }
  float T = s[1536];                            // 512th largest
  #pragma unroll
  for (int h = 0; h < 2; h++) {
    int i = tid + h * 1024;
    float v = s[i];
    if (v > T && (i == 0 || s[i - 1] <= T)) sFG = i;
    if (v == T && (i == 0 || s[i - 1] < T)) sFE = i;
  }
  __syncthreads();
  int cGt = 2048 - sFG;
  int cEq = sFG - sFE;
  int need = 512 - cGt;
  if (need == cEq) {                            // generic: take all >= T
    #pragma unroll
    for (int h = 0; h < 2; h++) {
      int i = tid + h * 1024;
      flags[b * 2048 + i] = (rs[i] >= T) ? 1 : 0;
    }
  } else if (tid == 0) {                        // tie-break (measure-zero)
    int taken = 0;
    for (int i = 0; i < 2048; i++) {
      float v = rs[i];
      int f = 0;
      if (v > T) f = 1;
      else if (v == T && taken < need) { f = 1; taken++; }
      flags[b * 2048 + i] = f;
    }
  }
}

// ---------- 3. fused: x2 = x + flag*LN1(x[rev]); out=x2; h2 = bf16(LN2(x2)) ----------
__global__ __launch_bounds__(256) void build_x2_ln2(const float* __restrict__ x,
    const int* __restrict__ flags,
    const float* __restrict__ g1, const float* __restrict__ b1,
    const float* __restrict__ g2, const float* __restrict__ b2,
    float* __restrict__ out, U16* __restrict__ h2) {
  int t = blockIdx.x, tid = threadIdx.x;
  __shared__ float sbuf[4];
  float4 xv = *(const float4*)(x + (size_t)t * 1024 + tid * 4);
  float4 x2v = xv;
  if (flags[t]) {                               // block-uniform branch
    int i = t >> 11, j = t & 2047;
    const float* xs = x + ((size_t)(i << 11) + (2047 - j)) * 1024;
    float4 sv = *(const float4*)(xs + tid * 4);
    float m = block_sum(sv.x + sv.y + sv.z + sv.w, sbuf, tid) * (1.f / 1024.f);
    float dx = sv.x - m, dy = sv.y - m, dz = sv.z - m, dw = sv.w - m;
    float var = block_sum(dx * dx + dy * dy + dz * dz + dw * dw, sbuf, tid) * (1.f / 1024.f);
    float rstd = rsqrtf(var + 1e-5f);
    float4 gv = *(const float4*)(g1 + tid * 4);
    float4 bv = *(const float4*)(b1 + tid * 4);
    x2v.x += dx * rstd * gv.x + bv.x;
    x2v.y += dy * rstd * gv.y + bv.y;
    x2v.z += dz * rstd * gv.z + bv.z;
    x2v.w += dw * rstd * gv.w + bv.w;
  }
  *(float4*)(out + (size_t)t * 1024 + tid * 4) = x2v;
  float m2 = block_sum(x2v.x + x2v.y + x2v.z + x2v.w, sbuf, tid) * (1.f / 1024.f);
  float dx = x2v.x - m2, dy = x2v.y - m2, dz = x2v.z - m2, dw = x2v.w - m2;
  float var2 = block_sum(dx * dx + dy * dy + dz * dz + dw * dw, sbuf, tid) * (1.f / 1024.f);
  float rstd2 = rsqrtf(var2 + 1e-5f);
  float4 gv = *(const float4*)(g2 + tid * 4);
  float4 bv = *(const float4*)(b2 + tid * 4);
  ushort4 hv;
  hv.x = bf_hi(dx * rstd2 * gv.x + bv.x);
  hv.y = bf_hi(dy * rstd2 * gv.y + bv.y);
  hv.z = bf_hi(dz * rstd2 * gv.z + bv.z);
  hv.w = bf_hi(dw * rstd2 * gv.w + bv.w);
  *(ushort4*)(h2 + (size_t)t * 1024 + tid * 4) = hv;
}

// ---------- 4. weight fp32 -> bf16 ----------
__global__ __launch_bounds__(256) void conv_w(const float* __restrict__ a, U16* __restrict__ o) {
  size_t idx = ((size_t)blockIdx.x * 256 + threadIdx.x) * 4;
  float4 v = *(const float4*)(a + idx);
  ushort4 hv;
  hv.x = bf_hi(v.x); hv.y = bf_hi(v.y); hv.z = bf_hi(v.z); hv.w = bf_hi(v.w);
  *(ushort4*)(o + idx) = hv;
}

// ---------- 5/6. bf16 GEMM: C = A(MxK) . B(NxK)^T ----------
// 128x128 tile, 4 waves (2x2 of 64x64), BK=64 bf16, m97 structure.
// LDS: A,B each [128 rows][64 bf16 = 8 slots of 16B], phys slot = logical ^ (row&7).
// Desk-check: each ds_read_b128 wave -> 8 lanes per 16B slot column (uniform; b128 minimum).
// EPI 0: gelu -> bf16 -> oB.  EPI 1: oF += acc+bias (residual RMW into d_out).
template <int KC, int NC, int EPI>
__global__ __launch_bounds__(256) void gemm_bf(
    const U16* __restrict__ A, const U16* __restrict__ B,
    const float* __restrict__ bias, U16* __restrict__ oB, float* __restrict__ oF) {
  __shared__ __align__(16) U16 lds[16384];      // 32KB: A 16KB | B 16KB
  U16* LA = lds;
  U16* LB = lds + 8192;

  int tid = threadIdx.x;
  int w = tid >> 6, l = tid & 63;
  constexpr int nbn = NC / 128;
  int nwg = gridDim.x;                          // %8==0 for all launches here
  int wg = blockIdx.x;
  wg = (wg & 7) * (nwg >> 3) + (wg >> 3);       // XCD-contiguous swizzle (bijective)
  int tm = wg / nbn, tn = wg % nbn;

  // staging: 1024 16B chunks each for A and B; chunk c -> LDS byte c*16,
  // row r=c>>3, phys slot s=c&7, logical slot sl = s ^ (r&7), k0 = sl*8
  size_t aoff[4], boff[4];
  #pragma unroll
  for (int p = 0; p < 4; p++) {
    int c = p * 256 + tid;
    int r = c >> 3;
    int sl = (c & 7) ^ (r & 7);
    aoff[p] = (size_t)(tm * 128 + r) * KC + sl * 8;
    boff[p] = (size_t)(tn * 128 + r) * KC + sl * 8;
  }

  int wm = w >> 1, wn = w & 1;
  int lr = l & 15, kg = l >> 4;
  int offa[4][2], offb[4][2];                   // ushort offsets, K-step invariant
  #pragma unroll
  for (int i = 0; i < 4; i++)
    #pragma unroll
    for (int h = 0; h < 2; h++) {
      int ra = wm * 64 + i * 16 + lr;
      offa[i][h] = ra * 64 + (((h * 4 + kg) ^ (ra & 7)) << 3);
      int rb = wn * 64 + i * 16 + lr;
      offb[i][h] = rb * 64 + (((h * 4 + kg) ^ (rb & 7)) << 3);
    }

  f32x4 acc[4][4];
  #pragma unroll
  for (int i = 0; i < 4; i++)
    #pragma unroll
    for (int j = 0; j < 4; j++) acc[i][j] = {0.f, 0.f, 0.f, 0.f};

  #pragma unroll 1
  for (int kt = 0; kt < KC; kt += 64) {
    #pragma unroll
    for (int p = 0; p < 4; p++) {
      gl_lds16(A + aoff[p] + kt, (char*)LA + (p * 256 + w * 64) * 16);
      gl_lds16(B + boff[p] + kt, (char*)LB + (p * 256 + w * 64) * 16);
    }
    __syncthreads();                            // drains vmcnt before reads

    short8 fa[4][2], fb[4][2];
    #pragma unroll
    for (int i = 0; i < 4; i++)
      #pragma unroll
      for (int h = 0; h < 2; h++) {
        fa[i][h] = *(const short8*)(LA + offa[i][h]);
        fb[i][h] = *(const short8*)(LB + offb[i][h]);
      }
    #pragma unroll
    for (int i = 0; i < 4; i++)
      #pragma unroll
      for (int j = 0; j < 4; j++) {
        acc[i][j] = __builtin_amdgcn_mfma_f32_16x16x32_bf16(fa[i][0], fb[j][0], acc[i][j], 0, 0, 0);
        acc[i][j] = __builtin_amdgcn_mfma_f32_16x16x32_bf16(fa[i][1], fb[j][1], acc[i][j], 0, 0, 0);
      }
    __syncthreads();
  }

  // epilogue; C/D map: col = lane&15, row = (lane>>4)*4 + reg (m89-verified)
  int gr0 = tm * 128 + wm * 64 + kg * 4;
  int gc0 = tn * 128 + wn * 64 + lr;
  #pragma unroll
  for (int j = 0; j < 4; j++) {
    int gc = gc0 + j * 16;
    float bv = bias[gc];
    #pragma unroll
    for (int i = 0; i < 4; i++) {
      #pragma unroll
      for (int r = 0; r < 4; r++) {
        size_t o = (size_t)(gr0 + i * 16 + r) * NC + gc;
        float v = acc[i][j][r] + bv;
        if (EPI == 0) {
          oB[o] = bf_hi(gelu_f(v));
        } else {
          oF[o] = oF[o] + v;                    // += x2 already in d_out
        }
      }
    }
  }
}

// ---------- launch ----------
extern "C" void kernel_launch(void* const* d_in, const int* in_sizes, int n_in,
                              void* d_out, int out_size, void* d_ws, size_t ws_size,
                              hipStream_t stream) {
  const float* x   = (const float*)d_in[0];
  const float* rw  = (const float*)d_in[1];
  const float* rb  = (const float*)d_in[2];
  const float* g1  = (const float*)d_in[3];
  const float* b1  = (const float*)d_in[4];
  // d_in[5..7] = wq,wk,wv: dead code in the reference
  const float* g2  = (const float*)d_in[8];
  const float* b2  = (const float*)d_in[9];
  const float* fcw = (const float*)d_in[10];
  const float* fcb = (const float*)d_in[11];
  const float* pjw = (const float*)d_in[12];
  const float* pjb = (const float*)d_in[13];
  float* out = (float*)d_out;
  (void)in_sizes; (void)n_in; (void)out_size;

  const size_t M = 16384;
  char* p = (char*)d_ws;
  U16* h2   = (U16*)p;  p += M * 1024 * 2;            // 33.55 MB
  U16* fw   = (U16*)p;  p += (size_t)4096 * 1024 * 2; //  8.39 MB
  U16* pw   = (U16*)p;  p += (size_t)4096 * 1024 * 2; //  8.39 MB
  float* rsc = (float*)p; p += (size_t)8 * 2048 * 4;
  int* flags = (int*)p;   p += (size_t)8 * 2048 * 4;
  size_t fixedB = (size_t)(p - (char*)d_ws);          // ~50.5 MB, 16B-aligned
  U16* act = (U16*)p;                                  // [CH][4096] bf16, reused per chunk

  // largest chunk (rows) whose act buffer fits
  size_t availB = (ws_size > fixedB) ? (ws_size - fixedB) : 0;
  int CH = 16384;
  while (CH > 2048 && (size_t)CH * 4096 * 2 > availB) CH >>= 1;
  if ((size_t)CH * 4096 * 2 > availB) return;         // < 67 MB total: cannot run

  router_kernel<<<4096, 256, 0, stream>>>(x, rw, rb, rsc);
  topk_kernel<<<8, 1024, 0, stream>>>(rsc, flags);
  build_x2_ln2<<<16384, 256, 0, stream>>>(x, flags, g1, b1, g2, b2, out, h2);
  conv_w<<<4096, 256, 0, stream>>>(fcw, fw);
  conv_w<<<4096, 256, 0, stream>>>(pjw, pw);

  for (int c0 = 0; c0 < (int)M; c0 += CH) {
    // GEMM1 chunk: [CH,1024] x [4096,1024]^T -> gelu -> act (bf16)
    gemm_bf<1024, 4096, 0><<<(CH / 128) * 32, 256, 0, stream>>>(
        h2 + (size_t)c0 * 1024, fw, fcb, act, nullptr);
    // GEMM2 chunk: [CH,4096] x [1024,4096]^T += out (x2)
    gemm_bf<4096, 1024, 1><<<(CH / 128) * 8, 256, 0, stream>>>(
        act, pw, pjb, nullptr, out + (size_t)c0 * 1024);
  }
}